// Round 6
// baseline (1619.107 us; speedup 1.0000x reference)
//
#include <hip/hip_runtime.h>
#include <hip/hip_fp16.h>

#define DIM 64
#define CHUNK 2048   // scan chunk: 256 threads x 8 elements

typedef float f4v __attribute__((ext_vector_type(4)));

// ---------------- CSR build kernels (combined user+item vertex space) ----------------
// Vertex space: users [0, NU), items [NU, NU+NI). deg/offs/cur/rs all length NU+NI.
// adj is ONE array of 2E entries: user segments first (positions [0,E)), item segments
// ([E,2E)). Neighbor ids stored LOCAL (item id for user rows, user id for item rows).

__global__ void hist_kernel(const int* __restrict__ row, const int* __restrict__ col,
                            int* __restrict__ deg, int NU, int E) {
    int e = blockIdx.x * blockDim.x + threadIdx.x;
    if (e < E) {
        atomicAdd(&deg[row[e]], 1);
        atomicAdd(&deg[NU + col[e]], 1);
    }
}

__global__ void fill_rsqrt(const int* __restrict__ deg, float* __restrict__ r, int n) {
    int i = blockIdx.x * blockDim.x + threadIdx.x;
    if (i < n) r[i] = rsqrtf(fmaxf((float)deg[i], 1.0f));
}

__global__ void partial_sums(const int* __restrict__ deg, int* __restrict__ bsum, int n) {
    __shared__ int s[256];
    int t = threadIdx.x;
    int base = blockIdx.x * CHUNK + t * 8;
    int loc = 0;
    for (int k = 0; k < 8; k++) { int j = base + k; if (j < n) loc += deg[j]; }
    s[t] = loc; __syncthreads();
    for (int ofs = 128; ofs > 0; ofs >>= 1) { if (t < ofs) s[t] += s[t + ofs]; __syncthreads(); }
    if (t == 0) bsum[blockIdx.x] = s[0];
}

// parallel exclusive scan of bsum[0..nb), nb <= 256
__global__ void scan_block(int* __restrict__ bsum, int nb) {
    __shared__ int s[256];
    int t = threadIdx.x;
    int x = (t < nb) ? bsum[t] : 0;
    s[t] = x; __syncthreads();
    for (int ofs = 1; ofs < 256; ofs <<= 1) {
        int y = (t >= ofs) ? s[t - ofs] : 0;
        __syncthreads();
        s[t] += y;
        __syncthreads();
    }
    if (t < nb) bsum[t] = s[t] - x;   // inclusive - self = exclusive
}

// exclusive scan of deg -> offs and cur (deg may alias cur)
__global__ void scan_chunk(const int* __restrict__ deg, int* __restrict__ offs,
                           int* __restrict__ cur, const int* __restrict__ bsum, int n) {
    __shared__ int s[256];
    int t = threadIdx.x;
    int base = blockIdx.x * CHUNK + t * 8;
    int v[8]; int loc = 0;
    for (int k = 0; k < 8; k++) { int j = base + k; v[k] = (j < n) ? deg[j] : 0; loc += v[k]; }
    s[t] = loc; __syncthreads();
    for (int ofs = 1; ofs < 256; ofs <<= 1) {
        int x = (t >= ofs) ? s[t - ofs] : 0;
        __syncthreads();
        s[t] += x;
        __syncthreads();
    }
    int excl = (t == 0) ? 0 : s[t - 1];
    int run = bsum[blockIdx.x] + excl;
    for (int k = 0; k < 8; k++) {
        int j = base + k;
        if (j < n) { offs[j] = run; cur[j] = run; }
        run += v[k];
    }
}

// Simple single-pass scatter. Binned-by-owner (XCD) variant (R3) did NOT reduce
// WRITE_SIZE (245 vs 248 MB); hbm ~16% of peak, VALUBusy ~0.5% -> bound by
// memory-side atomic/request throughput, which locality can't fix. Keep simple.
__global__ void scatter_kernel(const int* __restrict__ row, const int* __restrict__ col,
                               const float* __restrict__ w, int has_w,
                               const float* __restrict__ rs,
                               int* __restrict__ cur, int2* __restrict__ adj,
                               int NU, int E) {
    int e = blockIdx.x * blockDim.x + threadIdx.x;
    if (e >= E) return;
    int r = row[e], c = col[e];
    float wv = has_w ? w[e] : 1.0f;
    float nrm = rs[r] * rs[NU + c] * wv;
    int nb = __float_as_int(nrm);
    int pu = atomicAdd(&cur[r], 1);
    adj[pu] = make_int2(c, nb);          // user row -> local item id
    int pi = atomicAdd(&cur[NU + c], 1);
    adj[pi] = make_int2(r, nb);          // item row -> user id
}

// ---------------- embedding kernels ----------------

// sum = src (fp32, the output buffer); h = fp16 working table (self state).
// NT stores: sum is next touched 2 layers later (guaranteed evicted), keep it
// out of L2 so gather rows stay resident.
__global__ void init_h(const float* __restrict__ src, float* __restrict__ sum,
                       uint2* __restrict__ h, int n4) {
    int i = blockIdx.x * blockDim.x + threadIdx.x;
    if (i < n4) {
        f4v v = __builtin_nontemporal_load(((const f4v*)src) + i);
        __builtin_nontemporal_store(v, ((f4v*)sum) + i);
        __half2 a = __floats2half2_rn(v.x, v.y);
        __half2 b = __floats2half2_rn(v.z, v.w);
        uint2 u; u.x = *(unsigned*)&a; u.y = *(unsigned*)&b;
        h[i] = u;
    }
}

// MERGED per-layer aggregate over the combined vertex space [0, NV):
// users (v<NU) gather from the item table, items from the user table — both read
// only layer-(l-1) state (matches reference). fp16 self chain; fp32 running sum.
//
// PAIR-FUSED SUM (R6): the epilogue at layer l holds BOTH e_l (self, just read)
// and e_{l+1} (fin) in registers. So the fp32 sum r/m/w runs only on odd layers:
//   l=1: sum += e1 + e2 ; l=3: sum = (sum + e3 + e4) * 0.2
// -> 2 sum passes instead of 4 (saves 512B/vertex/graph·2, ~400MB total),
// zero extra loads. NT load/store on sum (reuse distance = 2 layers >> L2).
//
// adj entries are read once per layer -> NT loads (don't evict gather rows).
//
// One wave per vertex; lane l = (slot q=l>>4, quad c=l&15): one uint2 (8B=4
// halves) per lane -> one wave-instruction gathers FOUR 128B rows. 8 nbrs/iter,
// branchless tail. Butterfly (xor16,32); lanes 0-15 (q==0) do the epilogue.
//
// Deg-0 early exit: out already holds e0 from init_h; deg-0 vertex appears in
// no adjacency list so its stale rows are never gathered. Exact for any input.
__global__ void aggregate(const int* __restrict__ offs, const int* __restrict__ endo,
                          const int2* __restrict__ adj,
                          const uint2* __restrict__ u_cur,
                          const uint2* __restrict__ i_cur,
                          uint2* __restrict__ u_new,
                          uint2* __restrict__ i_new,
                          float* __restrict__ sum_u,
                          float* __restrict__ sum_i,
                          float scale, int wh, int dosum, int NU, int NV) {
    int v = blockIdx.x * (blockDim.x >> 6) + (threadIdx.x >> 6);
    if (v >= NV) return;
    v = __builtin_amdgcn_readfirstlane(v);     // provably wave-uniform -> s_ ops
    int s = offs[v], e = endo[v];
    if (s == e) return;                        // deg-0: output already correct (== e0)

    bool isU = v < NU;                         // wave-uniform
    const uint2* src   = isU ? i_cur : u_cur;  // gather the OTHER side's old table
    const uint2* selfT = isU ? u_cur : i_cur;
    uint2*       dstT  = isU ? u_new : i_new;
    float*       sum   = isU ? sum_u : sum_i;
    int vl = isU ? v : v - NU;                 // local row in its table

    int l = threadIdx.x & 63;
    int q = l >> 4;                            // neighbor slot within a 4-group
    int c = l & 15;                            // element quad (elements 4c..4c+3)

    float ax = 0.f, ay = 0.f, az = 0.f, aw = 0.f;
    for (int i = s; i < e; i += 8) {
        int i0 = i + q;
        int i1 = i + 4 + q;
        long long a0 = __builtin_nontemporal_load((const long long*)(adj + min(i0, e - 1)));
        long long a1 = __builtin_nontemporal_load((const long long*)(adj + min(i1, e - 1)));
        int id0 = (int)(a0 & 0xffffffffLL);
        int id1 = (int)(a1 & 0xffffffffLL);
        float w0 = (i0 < e) ? __int_as_float((int)(a0 >> 32)) : 0.0f;
        float w1 = (i1 < e) ? __int_as_float((int)(a1 >> 32)) : 0.0f;
        uint2 h0 = src[(size_t)id0 * 16 + c];   // 4 halves of neighbor row
        uint2 h1 = src[(size_t)id1 * 16 + c];
        float2 f00 = __half22float2(*(__half2*)&h0.x);
        float2 f01 = __half22float2(*(__half2*)&h0.y);
        float2 f10 = __half22float2(*(__half2*)&h1.x);
        float2 f11 = __half22float2(*(__half2*)&h1.y);
        ax += f00.x * w0; ay += f00.y * w0; az += f01.x * w0; aw += f01.y * w0;
        ax += f10.x * w1; ay += f10.y * w1; az += f11.x * w1; aw += f11.y * w1;
    }
    // reduce across the 4 neighbor slots (lanes l, l^16, l^32, l^48 share c)
    ax += __shfl_xor(ax, 16); ay += __shfl_xor(ay, 16);
    az += __shfl_xor(az, 16); aw += __shfl_xor(aw, 16);
    ax += __shfl_xor(ax, 32); ay += __shfl_xor(ay, 32);
    az += __shfl_xor(az, 32); aw += __shfl_xor(aw, 32);

    if (q == 0) {
        size_t ro = (size_t)vl * 16 + c;       // uint2 AND float4 row index
        uint2 hs = selfT[ro];
        float2 s01 = __half22float2(*(__half2*)&hs.x);
        float2 s23 = __half22float2(*(__half2*)&hs.y);
        float4 fin;
        fin.x = s01.x + ax; fin.y = s01.y + ay; fin.z = s23.x + az; fin.w = s23.y + aw;
        if (wh) {
            __half2 hA = __floats2half2_rn(fin.x, fin.y);
            __half2 hB = __floats2half2_rn(fin.z, fin.w);
            uint2 hw2; hw2.x = *(unsigned*)&hA; hw2.y = *(unsigned*)&hB;
            dstT[ro] = hw2;
        }
        if (dosum) {
            f4v sm = __builtin_nontemporal_load(((const f4v*)sum) + ro);
            sm.x = (sm.x + s01.x + fin.x) * scale;
            sm.y = (sm.y + s01.y + fin.y) * scale;
            sm.z = (sm.z + s23.x + fin.z) * scale;
            sm.w = (sm.w + s23.y + fin.w) * scale;
            __builtin_nontemporal_store(sm, ((f4v*)sum) + ro);
        }
    }
}

// ---------------- host ----------------

static inline int cdiv(long long a, int b) { return (int)((a + b - 1) / b); }

extern "C" void kernel_launch(void* const* d_in, const int* in_sizes, int n_in,
                              void* d_out, int out_size, void* d_ws, size_t ws_size,
                              hipStream_t stream) {
    const int*   ei  = (const int*)d_in[0];      // (2, E_POS)
    const int*   nei = (const int*)d_in[1];      // (2, E_NEG)
    const float* ew  = (const float*)d_in[2];    // (E_POS,)
    const float* uep = (const float*)d_in[3];
    const float* iep = (const float*)d_in[4];
    const float* uen = (const float*)d_in[5];
    const float* ien = (const float*)d_in[6];
    float* out = (float*)d_out;

    const int E_POS = in_sizes[2];
    const int E_NEG = in_sizes[1] / 2;
    const int NU = in_sizes[3] / DIM;
    const int NI = in_sizes[4] / DIM;
    const int NV = NU + NI;
    const int NTOT = NV * DIM;

    // ---- workspace layout (4-byte units) ----
    char* ws = (char*)d_ws;
    size_t off = 0;
    auto alloc = [&](size_t elems4) { void* p = ws + off; off += elems4 * 4; return p; };
    uint2* u_h0 = (uint2*)alloc((size_t)NU * DIM / 2);  // user fp16 ping (NU*DIM halves)
    uint2* u_h1 = (uint2*)alloc((size_t)NU * DIM / 2);  // user fp16 pong
    uint2* i_h0 = (uint2*)alloc((size_t)NI * DIM / 2);  // item fp16 ping
    uint2* i_h1 = (uint2*)alloc((size_t)NI * DIM / 2);  // item fp16 pong
    int*   offs = (int*)alloc(NV);
    int*   cur  = (int*)alloc(NV);                      // deg -> cursor -> end
    float* rs   = (float*)alloc(NV);
    int*   bsum = (int*)alloc(256);
    int2*  adj  = (int2*)alloc((size_t)E_POS * 4);      // 2*E_POS entries x int2

    const int B = 256;
    const int nb = cdiv(NV, CHUNK);                     // <= 256 required by scan_block

    for (int g = 0; g < 2; ++g) {
        const int    E   = g == 0 ? E_POS : E_NEG;
        const int*   row = g == 0 ? ei : nei;
        const int*   col = row + E;
        const float* wv  = g == 0 ? ew : nullptr;
        const float* ue0 = g == 0 ? uep : uen;
        const float* ie0 = g == 0 ? iep : ien;
        float* sum_u = out + (size_t)g * NTOT;
        float* sum_i = sum_u + (size_t)NU * DIM;

        // ---- CSR build (combined vertex space, once per graph) ----
        hipMemsetAsync(cur, 0, (size_t)NV * sizeof(int), stream);
        hist_kernel<<<cdiv(E, B), B, 0, stream>>>(row, col, cur, NU, E);
        fill_rsqrt<<<cdiv(NV, B), B, 0, stream>>>(cur, rs, NV);
        partial_sums<<<nb, B, 0, stream>>>(cur, bsum, NV);
        scan_block<<<1, 256, 0, stream>>>(bsum, nb);
        scan_chunk<<<nb, B, 0, stream>>>(cur, offs, cur, bsum, NV);
        scatter_kernel<<<cdiv(E, B), B, 0, stream>>>(row, col, wv, g == 0 ? 1 : 0,
                                                     rs, cur, adj, NU, E);
        // after scatter: cur[v] == offs[v] + deg[v] (end offsets)

        // ---- init running sums (output) + fp16 working tables ----
        init_h<<<cdiv(NU * DIM / 4, B), B, 0, stream>>>(ue0, sum_u, u_h0, NU * DIM / 4);
        init_h<<<cdiv(NI * DIM / 4, B), B, 0, stream>>>(ie0, sum_i, i_h0, NI * DIM / 4);

        uint2* ucur = u_h0; uint2* unew = u_h1;
        uint2* icur = i_h0; uint2* inew = i_h1;
        for (int l = 0; l < 4; ++l) {
            float scale = (l == 3) ? 0.2f : 1.0f;
            int wh = (l == 3) ? 0 : 1;    // last-layer outputs are never gathered
            int dosum = (l & 1);          // pair-fused: sum += self(e_l) + fin(e_{l+1})
            aggregate<<<cdiv(NV, 4), B, 0, stream>>>(
                offs, cur, adj, ucur, icur, unew, inew, sum_u, sum_i,
                scale, wh, dosum, NU, NV);
            uint2* t;
            t = ucur; ucur = unew; unew = t;
            t = icur; icur = inew; inew = t;
        }
    }
}

// Round 9
// 1512.317 us; speedup vs baseline: 1.0706x; 1.0706x over previous
//
#include <hip/hip_runtime.h>
#include <hip/hip_fp16.h>

#define DIM 64
#define CHUNK 2048   // scan chunk: 256 threads x 8 elements

// ---------------- CSR build kernels (combined user+item vertex space) ----------------
// Vertex space: users [0, NU), items [NU, NU+NI). deg/offs/cur/rs all length NU+NI.
// adj is ONE array of 2E entries: user segments first (positions [0,E)), item segments
// ([E,2E)). Neighbor ids stored LOCAL (item id for user rows, user id for item rows).

__global__ void hist_kernel(const int* __restrict__ row, const int* __restrict__ col,
                            int* __restrict__ deg, int NU, int E) {
    int e = blockIdx.x * blockDim.x + threadIdx.x;
    if (e < E) {
        atomicAdd(&deg[row[e]], 1);
        atomicAdd(&deg[NU + col[e]], 1);
    }
}

__global__ void fill_rsqrt(const int* __restrict__ deg, float* __restrict__ r, int n) {
    int i = blockIdx.x * blockDim.x + threadIdx.x;
    if (i < n) r[i] = rsqrtf(fmaxf((float)deg[i], 1.0f));
}

__global__ void partial_sums(const int* __restrict__ deg, int* __restrict__ bsum, int n) {
    __shared__ int s[256];
    int t = threadIdx.x;
    int base = blockIdx.x * CHUNK + t * 8;
    int loc = 0;
    for (int k = 0; k < 8; k++) { int j = base + k; if (j < n) loc += deg[j]; }
    s[t] = loc; __syncthreads();
    for (int ofs = 128; ofs > 0; ofs >>= 1) { if (t < ofs) s[t] += s[t + ofs]; __syncthreads(); }
    if (t == 0) bsum[blockIdx.x] = s[0];
}

// parallel exclusive scan of bsum[0..nb), nb <= 256
__global__ void scan_block(int* __restrict__ bsum, int nb) {
    __shared__ int s[256];
    int t = threadIdx.x;
    int x = (t < nb) ? bsum[t] : 0;
    s[t] = x; __syncthreads();
    for (int ofs = 1; ofs < 256; ofs <<= 1) {
        int y = (t >= ofs) ? s[t - ofs] : 0;
        __syncthreads();
        s[t] += y;
        __syncthreads();
    }
    if (t < nb) bsum[t] = s[t] - x;   // inclusive - self = exclusive
}

// exclusive scan of deg -> offs and cur (deg may alias cur)
__global__ void scan_chunk(const int* __restrict__ deg, int* __restrict__ offs,
                           int* __restrict__ cur, const int* __restrict__ bsum, int n) {
    __shared__ int s[256];
    int t = threadIdx.x;
    int base = blockIdx.x * CHUNK + t * 8;
    int v[8]; int loc = 0;
    for (int k = 0; k < 8; k++) { int j = base + k; v[k] = (j < n) ? deg[j] : 0; loc += v[k]; }
    s[t] = loc; __syncthreads();
    for (int ofs = 1; ofs < 256; ofs <<= 1) {
        int x = (t >= ofs) ? s[t - ofs] : 0;
        __syncthreads();
        s[t] += x;
        __syncthreads();
    }
    int excl = (t == 0) ? 0 : s[t - 1];
    int run = bsum[blockIdx.x] + excl;
    for (int k = 0; k < 8; k++) {
        int j = base + k;
        if (j < n) { offs[j] = run; cur[j] = run; }
        run += v[k];
    }
}

// Simple single-pass scatter. Binned-by-owner (XCD) variant (R3) did NOT reduce
// WRITE_SIZE; bound by memory-side atomic/request throughput. NOTE R6: this
// unchanged kernel varied 200->257us across runs — ±10% dispatch noise here.
__global__ void scatter_kernel(const int* __restrict__ row, const int* __restrict__ col,
                               const float* __restrict__ w, int has_w,
                               const float* __restrict__ rs,
                               int* __restrict__ cur, int2* __restrict__ adj,
                               int NU, int E) {
    int e = blockIdx.x * blockDim.x + threadIdx.x;
    if (e >= E) return;
    int r = row[e], c = col[e];
    float wv = has_w ? w[e] : 1.0f;
    float nrm = rs[r] * rs[NU + c] * wv;
    int nb = __float_as_int(nrm);
    int pu = atomicAdd(&cur[r], 1);
    adj[pu] = make_int2(c, nb);          // user row -> local item id
    int pi = atomicAdd(&cur[NU + c], 1);
    adj[pi] = make_int2(r, nb);          // item row -> user id
}

// ---------------- embedding kernels ----------------

// sum = src (fp32, the output buffer); h = fp16 working table (self state).
// Plain stores — R6 showed NT hints backfire here (adj is L3-resident and
// re-read 4x/graph; NT bypassed that reuse: 1544->1619us regression).
__global__ void init_h(const float* __restrict__ src, float* __restrict__ sum,
                       uint2* __restrict__ h, int n4) {
    int i = blockIdx.x * blockDim.x + threadIdx.x;
    if (i < n4) {
        float4 v = ((const float4*)src)[i];
        ((float4*)sum)[i] = v;
        __half2 a = __floats2half2_rn(v.x, v.y);
        __half2 b = __floats2half2_rn(v.z, v.w);
        uint2 u; u.x = *(unsigned*)&a; u.y = *(unsigned*)&b;
        h[i] = u;
    }
}

// MERGED per-layer aggregate over the combined vertex space [0, NV):
// users (v<NU) gather from the item table, items from the user table — both read
// only layer-(l-1) state (matches reference). fp16 self chain; fp32 running sum.
//
// PAIR-FUSED SUM: the epilogue at layer l holds BOTH e_l (self, just read) and
// e_{l+1} (fin) in registers, so the fp32 sum r/m/w runs only on odd layers:
//   l=1: sum += e1 + e2 ; l=3: sum = (sum + e3 + e4) * 0.2
// -> 2 sum passes instead of 4 (~400MB saved across both graphs), zero extra loads.
// Same floating-point series as the reference grouping (e1,e3 from fp16 store).
//
// One wave per vertex; lane l = (slot q=l>>4, quad c=l&15): one uint2 (8B=4
// halves) per lane -> one wave-instruction gathers FOUR 128B rows. 8 nbrs/iter,
// branchless tail. Butterfly (xor16,32); lanes 0-15 (q==0) do the epilogue.
//
// Deg-0 early exit: out already holds e0 from init_h; deg-0 vertex appears in
// no adjacency list so its stale rows are never gathered. Exact for any input.
__global__ void aggregate(const int* __restrict__ offs, const int* __restrict__ endo,
                          const int2* __restrict__ adj,
                          const uint2* __restrict__ u_cur,
                          const uint2* __restrict__ i_cur,
                          uint2* __restrict__ u_new,
                          uint2* __restrict__ i_new,
                          float* __restrict__ sum_u,
                          float* __restrict__ sum_i,
                          float scale, int wh, int dosum, int NU, int NV) {
    int v = blockIdx.x * (blockDim.x >> 6) + (threadIdx.x >> 6);
    if (v >= NV) return;
    v = __builtin_amdgcn_readfirstlane(v);     // provably wave-uniform -> s_ ops
    int s = offs[v], e = endo[v];
    if (s == e) return;                        // deg-0: output already correct (== e0)

    bool isU = v < NU;                         // wave-uniform
    const uint2* src   = isU ? i_cur : u_cur;  // gather the OTHER side's old table
    const uint2* selfT = isU ? u_cur : i_cur;
    uint2*       dstT  = isU ? u_new : i_new;
    float*       sum   = isU ? sum_u : sum_i;
    int vl = isU ? v : v - NU;                 // local row in its table

    int l = threadIdx.x & 63;
    int q = l >> 4;                            // neighbor slot within a 4-group
    int c = l & 15;                            // element quad (elements 4c..4c+3)

    float ax = 0.f, ay = 0.f, az = 0.f, aw = 0.f;
    for (int i = s; i < e; i += 8) {
        int i0 = i + q;
        int i1 = i + 4 + q;
        int2 m0 = adj[min(i0, e - 1)];
        int2 m1 = adj[min(i1, e - 1)];
        float w0 = (i0 < e) ? __int_as_float(m0.y) : 0.0f;
        float w1 = (i1 < e) ? __int_as_float(m1.y) : 0.0f;
        uint2 h0 = src[(size_t)m0.x * 16 + c];   // 4 halves of neighbor row
        uint2 h1 = src[(size_t)m1.x * 16 + c];
        float2 f00 = __half22float2(*(__half2*)&h0.x);
        float2 f01 = __half22float2(*(__half2*)&h0.y);
        float2 f10 = __half22float2(*(__half2*)&h1.x);
        float2 f11 = __half22float2(*(__half2*)&h1.y);
        ax += f00.x * w0; ay += f00.y * w0; az += f01.x * w0; aw += f01.y * w0;
        ax += f10.x * w1; ay += f10.y * w1; az += f11.x * w1; aw += f11.y * w1;
    }
    // reduce across the 4 neighbor slots (lanes l, l^16, l^32, l^48 share c)
    ax += __shfl_xor(ax, 16); ay += __shfl_xor(ay, 16);
    az += __shfl_xor(az, 16); aw += __shfl_xor(aw, 16);
    ax += __shfl_xor(ax, 32); ay += __shfl_xor(ay, 32);
    az += __shfl_xor(az, 32); aw += __shfl_xor(aw, 32);

    if (q == 0) {
        size_t ro = (size_t)vl * 16 + c;       // uint2 AND float4 row index
        uint2 hs = selfT[ro];
        float2 s01 = __half22float2(*(__half2*)&hs.x);
        float2 s23 = __half22float2(*(__half2*)&hs.y);
        float4 fin;
        fin.x = s01.x + ax; fin.y = s01.y + ay; fin.z = s23.x + az; fin.w = s23.y + aw;
        if (wh) {
            __half2 hA = __floats2half2_rn(fin.x, fin.y);
            __half2 hB = __floats2half2_rn(fin.z, fin.w);
            uint2 hw2; hw2.x = *(unsigned*)&hA; hw2.y = *(unsigned*)&hB;
            dstT[ro] = hw2;
        }
        if (dosum) {
            float4 sm = ((const float4*)sum)[ro];
            sm.x = (sm.x + s01.x + fin.x) * scale;
            sm.y = (sm.y + s01.y + fin.y) * scale;
            sm.z = (sm.z + s23.x + fin.z) * scale;
            sm.w = (sm.w + s23.y + fin.w) * scale;
            ((float4*)sum)[ro] = sm;
        }
    }
}

// ---------------- host ----------------

static inline int cdiv(long long a, int b) { return (int)((a + b - 1) / b); }

extern "C" void kernel_launch(void* const* d_in, const int* in_sizes, int n_in,
                              void* d_out, int out_size, void* d_ws, size_t ws_size,
                              hipStream_t stream) {
    const int*   ei  = (const int*)d_in[0];      // (2, E_POS)
    const int*   nei = (const int*)d_in[1];      // (2, E_NEG)
    const float* ew  = (const float*)d_in[2];    // (E_POS,)
    const float* uep = (const float*)d_in[3];
    const float* iep = (const float*)d_in[4];
    const float* uen = (const float*)d_in[5];
    const float* ien = (const float*)d_in[6];
    float* out = (float*)d_out;

    const int E_POS = in_sizes[2];
    const int E_NEG = in_sizes[1] / 2;
    const int NU = in_sizes[3] / DIM;
    const int NI = in_sizes[4] / DIM;
    const int NV = NU + NI;
    const int NTOT = NV * DIM;

    // ---- workspace layout (4-byte units) ----
    char* ws = (char*)d_ws;
    size_t off = 0;
    auto alloc = [&](size_t elems4) { void* p = ws + off; off += elems4 * 4; return p; };
    uint2* u_h0 = (uint2*)alloc((size_t)NU * DIM / 2);  // user fp16 ping (NU*DIM halves)
    uint2* u_h1 = (uint2*)alloc((size_t)NU * DIM / 2);  // user fp16 pong
    uint2* i_h0 = (uint2*)alloc((size_t)NI * DIM / 2);  // item fp16 ping
    uint2* i_h1 = (uint2*)alloc((size_t)NI * DIM / 2);  // item fp16 pong
    int*   offs = (int*)alloc(NV);
    int*   cur  = (int*)alloc(NV);                      // deg -> cursor -> end
    float* rs   = (float*)alloc(NV);
    int*   bsum = (int*)alloc(256);
    int2*  adj  = (int2*)alloc((size_t)E_POS * 4);      // 2*E_POS entries x int2

    const int B = 256;
    const int nb = cdiv(NV, CHUNK);                     // <= 256 required by scan_block

    for (int g = 0; g < 2; ++g) {
        const int    E   = g == 0 ? E_POS : E_NEG;
        const int*   row = g == 0 ? ei : nei;
        const int*   col = row + E;
        const float* wv  = g == 0 ? ew : nullptr;
        const float* ue0 = g == 0 ? uep : uen;
        const float* ie0 = g == 0 ? iep : ien;
        float* sum_u = out + (size_t)g * NTOT;
        float* sum_i = sum_u + (size_t)NU * DIM;

        // ---- CSR build (combined vertex space, once per graph) ----
        hipMemsetAsync(cur, 0, (size_t)NV * sizeof(int), stream);
        hist_kernel<<<cdiv(E, B), B, 0, stream>>>(row, col, cur, NU, E);
        fill_rsqrt<<<cdiv(NV, B), B, 0, stream>>>(cur, rs, NV);
        partial_sums<<<nb, B, 0, stream>>>(cur, bsum, NV);
        scan_block<<<1, 256, 0, stream>>>(bsum, nb);
        scan_chunk<<<nb, B, 0, stream>>>(cur, offs, cur, bsum, NV);
        scatter_kernel<<<cdiv(E, B), B, 0, stream>>>(row, col, wv, g == 0 ? 1 : 0,
                                                     rs, cur, adj, NU, E);
        // after scatter: cur[v] == offs[v] + deg[v] (end offsets)

        // ---- init running sums (output) + fp16 working tables ----
        init_h<<<cdiv(NU * DIM / 4, B), B, 0, stream>>>(ue0, sum_u, u_h0, NU * DIM / 4);
        init_h<<<cdiv(NI * DIM / 4, B), B, 0, stream>>>(ie0, sum_i, i_h0, NI * DIM / 4);

        uint2* ucur = u_h0; uint2* unew = u_h1;
        uint2* icur = i_h0; uint2* inew = i_h1;
        for (int l = 0; l < 4; ++l) {
            float scale = (l == 3) ? 0.2f : 1.0f;
            int wh = (l == 3) ? 0 : 1;    // last-layer outputs are never gathered
            int dosum = (l & 1);          // pair-fused: sum += self(e_l) + fin(e_{l+1})
            aggregate<<<cdiv(NV, 4), B, 0, stream>>>(
                offs, cur, adj, ucur, icur, unew, inew, sum_u, sum_i,
                scale, wh, dosum, NU, NV);
            uint2* t;
            t = ucur; ucur = unew; unew = t;
            t = icur; icur = inew; inew = t;
        }
    }
}